// Round 10
// baseline (171.815 us; speedup 1.0000x reference)
//
#include <hip/hip_runtime.h>
#include <hip/hip_bf16.h>
#include <math.h>

#define NNODES 131072
#define BW 16   // nodes per (single-wave) block

typedef __attribute__((ext_vector_type(8))) short bf16x8;
typedef __attribute__((ext_vector_type(4))) float f32x4;

// bf16 weights (prep): W_h [128*64] @0 | W_s [128*256] @8192 | W_g [64*128] @40960
__device__ short g_w[49152];
// bf16 fused weight Wc[o][v] = sum_h W_V[o][h]*W_h[h][v], [64*64] row-major
__device__ short g_wc[4096];

__device__ __forceinline__ short f2b(float f) {
  union { float f; unsigned u; } x; x.f = f;
  unsigned r = x.u + 0x7fffu + ((x.u >> 16) & 1u);
  return (short)(r >> 16);
}
__device__ __forceinline__ short c2b(float f) {
  __hip_bfloat16 h = __float2bfloat16(f);
  return *reinterpret_cast<short*>(&h);
}

__global__ void prep_kernel(const float* __restrict__ W_h, const float* __restrict__ W_V,
                            const float* __restrict__ W_s_w, const float* __restrict__ W_g_w) {
  int b = blockIdx.x;
  if (b < 48) {
    int i4 = (b * 256 + threadIdx.x) * 4;
    const float* src;
    if (i4 < 8192)       src = W_h   + i4;
    else if (i4 < 40960) src = W_s_w + (i4 - 8192);
    else                 src = W_g_w + (i4 - 40960);
    float4 q = *(const float4*)src;
    short4 p;
    p.x = f2b(q.x); p.y = f2b(q.y); p.z = f2b(q.z); p.w = f2b(q.w);
    *(short4*)(g_w + i4) = p;
  } else {
    int gid = (b - 48) * 256 + threadIdx.x;   // 0..1023
    int o  = gid >> 4;
    int v0 = (gid & 15) * 4;
    float a0 = 0.f, a1 = 0.f, a2 = 0.f, a3 = 0.f;
    #pragma unroll 8
    for (int h = 0; h < 128; ++h) {
      float wv = W_V[o * 128 + h];
      float4 wh = *(const float4*)(W_h + h * 64 + v0);
      a0 += wv * wh.x; a1 += wv * wh.y; a2 += wv * wh.z; a3 += wv * wh.w;
    }
    short4 p;
    p.x = f2b(a0); p.y = f2b(a1); p.z = f2b(a2); p.w = f2b(a3);
    *(short4*)(g_wc + o * 64 + v0) = p;
  }
}

// One wave = one block = 16 nodes; zero inter-wave coupling; all barriers 1-wave (~free).
// LDS 6144 B/block (key change vs R9's 12288 -> LDS no longer the occupancy cap):
//   NORM @0 [16][256B] bf16 swz  ->(after GEMM3 reads)->  SOUT @0 same layout
//   VST  @0 [8][768B] f32 swz  (overlay; V_out stored in two 8-node rounds)
// V/s MFMA A-frags load DIRECTLY from global; single-wave DS in-order execution
// makes all overlays safe (reads precede overwrites in program order).

__global__ __launch_bounds__(64, 4)
void gvp_kernel(const float* __restrict__ s_in, const float* __restrict__ V_in,
                const float* __restrict__ W_s_b, const float* __restrict__ W_g_b,
                float* __restrict__ s_out_g, float* __restrict__ V_out_g)
{
  __shared__ __align__(16) char smem[6144];
  char* const NORM = smem;
  char* const SOUT = smem;
  char* const VSTb = smem;

  const short* const g_wh = g_w;
  const short* const g_ws = g_w + 8192;
  const short* const g_wg = g_w + 40960;

  const int lane = threadIdx.x;     // 0..63
  const int l15  = lane & 15;
  const int g    = lane >> 4;       // 0..3
  const int k8   = g << 3;          // A/B frag k-offset
  const long n0  = (long)blockIdx.x * BW;

  // ---- V A-frags direct from global: af[c][ks], rows c*16+l15, k = ks*32+k8+j ----
  bf16x8 af[3][2];
  #pragma unroll
  for (int ks = 0; ks < 2; ++ks) {
    const float* vp = V_in + (n0 + l15) * 192 + (ks * 32 + k8) * 3;  // 96B contiguous
    float b[24];
    #pragma unroll
    for (int i = 0; i < 6; ++i) *(float4*)(b + 4 * i) = *(const float4*)(vp + 4 * i);
    #pragma unroll
    for (int c = 0; c < 3; ++c) {
      bf16x8 p;
      #pragma unroll
      for (int j = 0; j < 8; ++j) p[j] = c2b(b[3 * j + c]);
      af[c][ks] = p;
    }
  }
  // ---- s A-frags direct from global: a3s[ks], rows l15, k = ks*32+k8+j ----
  bf16x8 a3s[4];
  #pragma unroll
  for (int ks = 0; ks < 4; ++ks) {
    const float* sp = s_in + (n0 + l15) * 128 + ks * 32 + k8;        // 32B contiguous
    float4 q0 = *(const float4*)sp;
    float4 q1 = *(const float4*)(sp + 4);
    bf16x8 p;
    p[0] = c2b(q0.x); p[1] = c2b(q0.y); p[2] = c2b(q0.z); p[3] = c2b(q0.w);
    p[4] = c2b(q1.x); p[5] = c2b(q1.y); p[6] = c2b(q1.z); p[7] = c2b(q1.w);
    a3s[ks] = p;
  }

  // ---- GEMM1 (Vh, 48x128 K=64) in two h-halves; norms straight to NORM LDS ----
  #pragma unroll
  for (int half = 0; half < 2; ++half) {
    f32x4 acc[3][4];
    #pragma unroll
    for (int c = 0; c < 3; ++c)
      #pragma unroll
      for (int hh = 0; hh < 4; ++hh) { f32x4 z = {0.f,0.f,0.f,0.f}; acc[c][hh] = z; }
    bf16x8 bh[4][2];
    #pragma unroll
    for (int hh = 0; hh < 4; ++hh)
      #pragma unroll
      for (int ks = 0; ks < 2; ++ks)
        bh[hh][ks] = *(const bf16x8*)(g_wh + ((half * 4 + hh) * 16 + l15) * 64 + ks * 32 + k8);
    #pragma unroll
    for (int c = 0; c < 3; ++c)
      #pragma unroll
      for (int hh = 0; hh < 4; ++hh) {
        acc[c][hh] = __builtin_amdgcn_mfma_f32_16x16x32_bf16(af[c][0], bh[hh][0], acc[c][hh], 0, 0, 0);
        acc[c][hh] = __builtin_amdgcn_mfma_f32_16x16x32_bf16(af[c][1], bh[hh][1], acc[c][hh], 0, 0, 0);
      }
    #pragma unroll
    for (int hh = 0; hh < 4; ++hh)
      #pragma unroll
      for (int i = 0; i < 4; ++i) {
        int nl = g * 4 + i;
        int h  = (half * 4 + hh) * 16 + l15;
        float x0 = acc[0][hh][i], x1 = acc[1][hh][i], x2 = acc[2][hh][i];
        float nrm = sqrtf(x0 * x0 + x1 * x1 + x2 * x2);
        *(short*)(NORM + nl * 256 + (((unsigned)(h * 2)) ^ ((unsigned)((nl & 15) << 4)))) = c2b(nrm);
      }
  }
  __syncthreads();  // 1-wave: ~free; orders NORM writes before reads

  // ---- GEMM3: s_out[16][128] = relu([s|norm]·W_s^T + b), K=256 ----
  f32x4 acc3[8];
  #pragma unroll
  for (int oo = 0; oo < 8; ++oo) { f32x4 z = {0.f,0.f,0.f,0.f}; acc3[oo] = z; }
  #pragma unroll
  for (int ks = 0; ks < 8; ++ks) {
    bf16x8 a;
    if (ks < 4) {
      a = a3s[ks];
    } else {
      int ko = (ks - 4) * 32 + k8;
      a = *(const bf16x8*)(NORM + l15 * 256 + (((unsigned)(ko * 2)) ^ ((unsigned)((l15 & 15) << 4))));
    }
    #pragma unroll
    for (int oo = 0; oo < 8; ++oo) {
      bf16x8 b = *(const bf16x8*)(g_ws + (oo * 16 + l15) * 256 + ks * 32 + k8);
      acc3[oo] = __builtin_amdgcn_mfma_f32_16x16x32_bf16(a, b, acc3[oo], 0, 0, 0);
    }
  }
  // epilogue: global stores + SOUT stage (overlays NORM; in-wave DS order is safe)
  {
    float bias[8];
    #pragma unroll
    for (int oo = 0; oo < 8; ++oo) bias[oo] = W_s_b[oo * 16 + l15];
    #pragma unroll
    for (int i = 0; i < 4; ++i) {
      int nl = g * 4 + i;
      long rowb = (n0 + nl) * 128;
      unsigned sw = (unsigned)((nl & 15) << 4);
      #pragma unroll
      for (int oo = 0; oo < 8; ++oo) {
        float v = fmaxf(acc3[oo][i] + bias[oo], 0.0f);
        s_out_g[rowb + oo * 16 + l15] = v;
        *(short*)(SOUT + nl * 256 + (((unsigned)((oo * 16 + l15) * 2)) ^ sw)) = c2b(v);
      }
    }
  }
  __syncthreads();  // orders SOUT writes before reads

  // ---- GEMM4: gate logits, 16x64 K=128 ----
  f32x4 acc4[4];
  #pragma unroll
  for (int oo = 0; oo < 4; ++oo) { f32x4 z = {0.f,0.f,0.f,0.f}; acc4[oo] = z; }
  #pragma unroll
  for (int ks = 0; ks < 4; ++ks) {
    int ko = ks * 32 + k8;
    bf16x8 a = *(const bf16x8*)(SOUT + l15 * 256 + (((unsigned)(ko * 2)) ^ ((unsigned)((l15 & 15) << 4))));
    #pragma unroll
    for (int oo = 0; oo < 4; ++oo) {
      bf16x8 b = *(const bf16x8*)(g_wg + (oo * 16 + l15) * 128 + ko);
      acc4[oo] = __builtin_amdgcn_mfma_f32_16x16x32_bf16(a, b, acc4[oo], 0, 0, 0);
    }
  }
  // gate factors in-lane (frees acc4)
  float sg[4][4];
  {
    #pragma unroll
    for (int oo = 0; oo < 4; ++oo) {
      float bg = W_g_b[oo * 16 + l15];
      #pragma unroll
      for (int i = 0; i < 4; ++i)
        sg[oo][i] = 1.0f / (1.0f + __expf(-(acc4[oo][i] + bg)));
    }
  }

  // ---- GEMM2 (deferred): V_out_pre via fused Wc on the still-live af frags ----
  f32x4 acc2[3][4];
  #pragma unroll
  for (int c = 0; c < 3; ++c)
    #pragma unroll
    for (int oo = 0; oo < 4; ++oo) { f32x4 z = {0.f,0.f,0.f,0.f}; acc2[c][oo] = z; }
  {
    bf16x8 bc[4][2];
    #pragma unroll
    for (int oo = 0; oo < 4; ++oo)
      #pragma unroll
      for (int ks = 0; ks < 2; ++ks)
        bc[oo][ks] = *(const bf16x8*)(g_wc + (oo * 16 + l15) * 64 + ks * 32 + k8);
    #pragma unroll
    for (int c = 0; c < 3; ++c)
      #pragma unroll
      for (int oo = 0; oo < 4; ++oo) {
        acc2[c][oo] = __builtin_amdgcn_mfma_f32_16x16x32_bf16(af[c][0], bc[oo][0], acc2[c][oo], 0, 0, 0);
        acc2[c][oo] = __builtin_amdgcn_mfma_f32_16x16x32_bf16(af[c][1], bc[oo][1], acc2[c][oo], 0, 0, 0);
      }
  }

  // ---- V_out in two 8-node rounds through 6KB VST (gate applied in-lane) ----
  #pragma unroll
  for (int r = 0; r < 2; ++r) {
    if ((g >> 1) == r) {
      // this half of the lanes owns nodes 8r..8r+7
      #pragma unroll
      for (int oo = 0; oo < 4; ++oo)
        #pragma unroll
        for (int i = 0; i < 4; ++i) {
          int nl_rel = ((g & 1) << 2) + i;       // 0..7
          int nl_abs = (r << 3) + nl_rel;        // == g*4+i
          unsigned sw = (unsigned)((nl_abs & 15) << 4);
          unsigned base = (unsigned)(nl_rel * 768);
          int o = oo * 16 + l15;
          *(float*)(VSTb + base + (((unsigned)((o * 3 + 0) * 4)) ^ sw)) = acc2[0][oo][i] * sg[oo][i];
          *(float*)(VSTb + base + (((unsigned)((o * 3 + 1) * 4)) ^ sw)) = acc2[1][oo][i] * sg[oo][i];
          *(float*)(VSTb + base + (((unsigned)((o * 3 + 2) * 4)) ^ sw)) = acc2[2][oo][i] * sg[oo][i];
        }
    }
    __syncthreads();  // 1-wave: orders VST writes before reads
    {
      float4* Vo = (float4*)(V_out_g + (n0 + (long)(r << 3)) * 192);
      #pragma unroll
      for (int j = 0; j < 6; ++j) {
        int f   = j * 64 + lane;               // 0..383 flat float4 idx in this round
        int nl_rel = (f * 1366) >> 16;         // f / 48
        int rem = f - nl_rel * 48;
        int nl_abs = (r << 3) + nl_rel;
        float4 q = *(const float4*)(VSTb + nl_rel * 768 +
                     (((unsigned)(rem * 16)) ^ ((unsigned)((nl_abs & 15) << 4))));
        Vo[f] = q;
      }
    }
    __syncthreads();  // round-0 reads done before round-1 overwrites
  }
}

extern "C" void kernel_launch(void* const* d_in, const int* in_sizes, int n_in,
                              void* d_out, int out_size, void* d_ws, size_t ws_size,
                              hipStream_t stream) {
  const float* s_in  = (const float*)d_in[0];
  const float* V_in  = (const float*)d_in[1];
  const float* W_h   = (const float*)d_in[2];
  const float* W_V   = (const float*)d_in[3];
  const float* W_s_w = (const float*)d_in[4];
  const float* W_s_b = (const float*)d_in[5];
  const float* W_g_w = (const float*)d_in[6];
  const float* W_g_b = (const float*)d_in[7];
  float* out = (float*)d_out;
  float* s_out_g = out;
  float* V_out_g = out + (size_t)NNODES * 128;
  hipLaunchKernelGGL(prep_kernel, dim3(52), dim3(256), 0, stream,
                     W_h, W_V, W_s_w, W_g_w);
  hipLaunchKernelGGL(gvp_kernel, dim3(NNODES / BW), dim3(64), 0, stream,
                     s_in, V_in, W_s_b, W_g_b, s_out_g, V_out_g);
}

// Round 11
// 167.463 us; speedup vs baseline: 1.0260x; 1.0260x over previous
//
#include <hip/hip_runtime.h>
#include <hip/hip_bf16.h>
#include <math.h>

#define NNODES 131072
#define BN 32

typedef __attribute__((ext_vector_type(8))) short bf16x8;
typedef __attribute__((ext_vector_type(4))) float f32x4;

// bf16 weights (prep): W_h [128*64] @0 | W_s [128*256] @8192 | W_g [64*128] @40960
__device__ short g_w[49152];
// bf16 fused weight Wc[o][v] = sum_h W_V[o][h]*W_h[h][v], [64*64] row-major
__device__ short g_wc[4096];

__device__ __forceinline__ short f2b(float f) {
  union { float f; unsigned u; } x; x.f = f;
  unsigned r = x.u + 0x7fffu + ((x.u >> 16) & 1u);
  return (short)(r >> 16);
}
__device__ __forceinline__ short c2b(float f) {
  __hip_bfloat16 h = __float2bfloat16(f);
  return *reinterpret_cast<short*>(&h);
}

__global__ void prep_kernel(const float* __restrict__ W_h, const float* __restrict__ W_V,
                            const float* __restrict__ W_s_w, const float* __restrict__ W_g_w) {
  int b = blockIdx.x;
  if (b < 48) {
    int i4 = (b * 256 + threadIdx.x) * 4;
    const float* src;
    if (i4 < 8192)       src = W_h   + i4;
    else if (i4 < 40960) src = W_s_w + (i4 - 8192);
    else                 src = W_g_w + (i4 - 40960);
    float4 q = *(const float4*)src;
    short4 p;
    p.x = f2b(q.x); p.y = f2b(q.y); p.z = f2b(q.z); p.w = f2b(q.w);
    *(short4*)(g_w + i4) = p;
  } else {
    int gid = (b - 48) * 256 + threadIdx.x;   // 0..1023
    int o  = gid >> 4;
    int v0 = (gid & 15) * 4;
    float a0 = 0.f, a1 = 0.f, a2 = 0.f, a3 = 0.f;
    #pragma unroll 8
    for (int h = 0; h < 128; ++h) {
      float wv = W_V[o * 128 + h];
      float4 wh = *(const float4*)(W_h + h * 64 + v0);
      a0 += wv * wh.x; a1 += wv * wh.y; a2 += wv * wh.z; a3 += wv * wh.w;
    }
    short4 p;
    p.x = f2b(a0); p.y = f2b(a1); p.z = f2b(a2); p.w = f2b(a3);
    *(short4*)(g_wc + o * 64 + v0) = p;
  }
}

// LDS (32768 B exactly -> 5 blocks/CU = 20 waves/CU):
//   Vt   @0     (12288): [96][64]  bf16 s128 swz  (dead after GEMM1 reads)
//   NORM @12288 (8192) : [32][128] bf16 s256 swz  (dead after GEMM3 norm-half)
//   VST  @0     (24576): [32][192] f32  (overlays Vt+NORM; written after B3)
//   SOUT @24576 (8192) : [32][128] bf16 s256 swz  (own region, never overlaid)
// SC arena DELETED: GEMM3's s A-frags load directly from global (16 aligned
// 128B lines per instruction; 4 waves read same addresses -> L1/L2-absorbed).
// Barriers: B1 (Vt ready), B2 (NORM ready), B3 (SOUT ready + NORM/Vt reads done),
//           B4 (VST ready).

__global__ __launch_bounds__(256, 5)
void gvp_kernel(const float* __restrict__ s_in, const float* __restrict__ V_in,
                const float* __restrict__ W_s_b, const float* __restrict__ W_g_b,
                float* __restrict__ s_out_g, float* __restrict__ V_out_g)
{
  __shared__ __align__(16) char smem[32768];
  char*  const Vt   = smem;
  float* const VST  = (float*)smem;
  char*  const NORM = smem + 12288;
  char*  const SOUT = smem + 24576;

  const short* const g_wh = g_w;
  const short* const g_ws = g_w + 8192;
  const short* const g_wg = g_w + 40960;

  const int t    = threadIdx.x;
  const int lane = t & 63;
  const int w    = t >> 6;
  const int l15  = lane & 15;
  const int lk8  = (lane >> 4) << 3;  // 0,8,16,24 : k-offset of A/B frag
  const int r4   = (lane >> 4) << 2;  // 0,4,8,12  : row-offset of C frag
  const long n0  = (long)blockIdx.x * BN;

  // ---- stage V tile: thread (nl, vg) loads 24 contiguous floats of node nl ----
  {
    const int nl = t >> 3;        // 0..31
    const int vg = t & 7;         // 0..7
    const int v0 = vg << 3;       // 0,8,..,56
    const float* vp = V_in + (n0 + nl) * 192 + v0 * 3;   // 96B contiguous
    float4 q0 = *(const float4*)(vp);
    float4 q1 = *(const float4*)(vp + 4);
    float4 q2 = *(const float4*)(vp + 8);
    float4 q3 = *(const float4*)(vp + 12);
    float4 q4 = *(const float4*)(vp + 16);
    float4 q5 = *(const float4*)(vp + 20);
    float fl[24];
    *(float4*)(fl)      = q0; *(float4*)(fl + 4)  = q1;
    *(float4*)(fl + 8)  = q2; *(float4*)(fl + 12) = q3;
    *(float4*)(fl + 16) = q4; *(float4*)(fl + 20) = q5;
    #pragma unroll
    for (int c = 0; c < 3; ++c) {
      int row = (c << 5) + nl;
      bf16x8 p;
      #pragma unroll
      for (int j = 0; j < 8; ++j) p[j] = c2b(fl[j * 3 + c]);
      unsigned a = (unsigned)(row * 128) + (((unsigned)(v0 * 2)) ^ (unsigned)((row & 7) << 4));
      *(bf16x8*)(Vt + a) = p;
    }
  }
  __syncthreads();  // B1: Vt visible

  // ---- GEMM1 (Vh) + GEMM2 (V_out_pre via fused Wc), shared Vt A-frags, K=64 ----
  f32x4 acc1[6][2];
  f32x4 acc2[6];
  #pragma unroll
  for (int rt = 0; rt < 6; ++rt) {
    f32x4 z = {0.f, 0.f, 0.f, 0.f};
    acc1[rt][0] = z; acc1[rt][1] = z; acc2[rt] = z;
  }
  {
    bf16x8 bf1[2][2];
    #pragma unroll
    for (int cc = 0; cc < 2; ++cc) {
      int h = ((2 * w + cc) << 4) + l15;
      #pragma unroll
      for (int ks = 0; ks < 2; ++ks)
        bf1[cc][ks] = *(const bf16x8*)(g_wh + h * 64 + (ks << 5) + lk8);
    }
    bf16x8 bc[2];
    {
      int o = (w << 4) + l15;
      bc[0] = *(const bf16x8*)(g_wc + o * 64 + lk8);
      bc[1] = *(const bf16x8*)(g_wc + o * 64 + 32 + lk8);
    }
    #pragma unroll
    for (int rt = 0; rt < 6; ++rt) {
      int row = (rt << 4) + l15;
      unsigned sw = (unsigned)((row & 7) << 4);
      bf16x8 af0 = *(const bf16x8*)(Vt + row * 128 + (((unsigned)(lk8 * 2)) ^ sw));
      bf16x8 af1 = *(const bf16x8*)(Vt + row * 128 + (((unsigned)((32 + lk8) * 2)) ^ sw));
      #pragma unroll
      for (int cc = 0; cc < 2; ++cc) {
        acc1[rt][cc] = __builtin_amdgcn_mfma_f32_16x16x32_bf16(af0, bf1[cc][0], acc1[rt][cc], 0, 0, 0);
        acc1[rt][cc] = __builtin_amdgcn_mfma_f32_16x16x32_bf16(af1, bf1[cc][1], acc1[rt][cc], 0, 0, 0);
      }
      acc2[rt] = __builtin_amdgcn_mfma_f32_16x16x32_bf16(af0, bc[0], acc2[rt], 0, 0, 0);
      acc2[rt] = __builtin_amdgcn_mfma_f32_16x16x32_bf16(af1, bc[1], acc2[rt], 0, 0, 0);
    }
  }

  // ---- s A-frags direct from global (issued early; used in GEMM3 s-half) ----
  bf16x8 a3s[2][4];
  #pragma unroll
  for (int rt = 0; rt < 2; ++rt)
    #pragma unroll
    for (int ks = 0; ks < 4; ++ks) {
      const float* sp = s_in + (n0 + (rt << 4) + l15) * 128 + (ks << 5) + lk8;
      float4 q0 = *(const float4*)sp;
      float4 q1 = *(const float4*)(sp + 4);
      bf16x8 p;
      p[0] = c2b(q0.x); p[1] = c2b(q0.y); p[2] = c2b(q0.z); p[3] = c2b(q0.w);
      p[4] = c2b(q1.x); p[5] = c2b(q1.y); p[6] = c2b(q1.z); p[7] = c2b(q1.w);
      a3s[rt][ks] = p;
    }

  // ---- Vh_norm -> NORM ----
  #pragma unroll
  for (int cc = 0; cc < 2; ++cc) {
    int col = ((2 * w + cc) << 4) + l15;
    #pragma unroll
    for (int rt = 0; rt < 2; ++rt) {
      #pragma unroll
      for (int i = 0; i < 4; ++i) {
        int nl = (rt << 4) + r4 + i;
        float x0 = acc1[rt][cc][i];
        float x1 = acc1[rt + 2][cc][i];
        float x2 = acc1[rt + 4][cc][i];
        float nrm = sqrtf(x0 * x0 + x1 * x1 + x2 * x2);
        unsigned a = (unsigned)(nl * 256) + (((unsigned)(col * 2)) ^ (unsigned)((nl & 7) << 4));
        *(short*)(NORM + a) = c2b(nrm);
      }
    }
  }
  __syncthreads();  // B2: NORM visible

  // ---- GEMM3: s_out = relu([s|norm]·W_s^T + b); 32x128, K=256 ----
  // wave w owns output cols [w*32, w*32+32): line-local stores
  f32x4 acc3[2][2];
  {
    f32x4 z = {0.f, 0.f, 0.f, 0.f};
    acc3[0][0] = z; acc3[0][1] = z; acc3[1][0] = z; acc3[1][1] = z;
  }
  #pragma unroll
  for (int ks = 0; ks < 8; ++ks) {
    bf16x8 b3[2];
    #pragma unroll
    for (int cc = 0; cc < 2; ++cc) {
      int o = (w << 5) + (cc << 4) + l15;
      b3[cc] = *(const bf16x8*)(g_ws + o * 256 + (ks << 5) + lk8);
    }
    #pragma unroll
    for (int rt = 0; rt < 2; ++rt) {
      bf16x8 a;
      if (ks < 4) {
        a = a3s[rt][ks];
      } else {
        int row = (rt << 4) + l15;
        unsigned sw = (unsigned)((row & 7) << 4);
        a = *(const bf16x8*)(NORM + row * 256 + (((unsigned)((((ks - 4) << 5) + lk8) * 2)) ^ sw));
      }
      acc3[rt][0] = __builtin_amdgcn_mfma_f32_16x16x32_bf16(a, b3[0], acc3[rt][0], 0, 0, 0);
      acc3[rt][1] = __builtin_amdgcn_mfma_f32_16x16x32_bf16(a, b3[1], acc3[rt][1], 0, 0, 0);
    }
  }

  // ---- s_out epilogue: line-local global stores + SOUT stage (own region) ----
  {
    float bias0 = W_s_b[(w << 5) + l15];
    float bias1 = W_s_b[(w << 5) + 16 + l15];
    #pragma unroll
    for (int rt = 0; rt < 2; ++rt) {
      #pragma unroll
      for (int i = 0; i < 4; ++i) {
        int row = (rt << 4) + r4 + i;
        unsigned sw = (unsigned)((row & 7) << 4);
        float v0 = fmaxf(acc3[rt][0][i] + bias0, 0.0f);
        float v1 = fmaxf(acc3[rt][1][i] + bias1, 0.0f);
        int col0 = (w << 5) + l15;
        s_out_g[(n0 + row) * 128 + col0]      = v0;
        s_out_g[(n0 + row) * 128 + col0 + 16] = v1;
        unsigned a0 = (unsigned)(row * 256) + (((unsigned)(col0 * 2)) ^ sw);
        unsigned a1 = (unsigned)(row * 256) + (((unsigned)((col0 + 16) * 2)) ^ sw);
        *(short*)(SOUT + a0) = c2b(v0);
        *(short*)(SOUT + a1) = c2b(v1);
      }
    }
  }
  __syncthreads();  // B3: SOUT ready; Vt/NORM reads all done -> VST overlay allowed

  // ---- GEMM4: gate = sigmoid(s_out·W_g^T + b); C-frag lane-aligned with acc2 ----
  f32x4 acc4[2];
  { f32x4 z = {0.f, 0.f, 0.f, 0.f}; acc4[0] = z; acc4[1] = z; }
  {
    int o = (w << 4) + l15;
    #pragma unroll
    for (int ks = 0; ks < 4; ++ks) {
      bf16x8 b4 = *(const bf16x8*)(g_wg + o * 128 + (ks << 5) + lk8);
      #pragma unroll
      for (int rt = 0; rt < 2; ++rt) {
        int row = (rt << 4) + l15;
        bf16x8 a = *(const bf16x8*)(SOUT + row * 256 +
                     (((unsigned)(((ks << 5) + lk8) * 2)) ^ ((unsigned)((row & 7) << 4))));
        acc4[rt] = __builtin_amdgcn_mfma_f32_16x16x32_bf16(a, b4, acc4[rt], 0, 0, 0);
      }
    }
  }

  // ---- gate apply (in-lane) -> VST [32][192] f32 (overlays Vt+NORM) ----
  {
    int col = (w << 4) + l15;
    float biasg = W_g_b[col];
    #pragma unroll
    for (int nlg = 0; nlg < 2; ++nlg) {
      #pragma unroll
      for (int i = 0; i < 4; ++i) {
        int nl = (nlg << 4) + r4 + i;
        float x = acc4[nlg][i] + biasg;
        float sg = 1.0f / (1.0f + __expf(-x));
        VST[nl * 192 + col * 3 + 0] = acc2[nlg][i]     * sg;
        VST[nl * 192 + col * 3 + 1] = acc2[2 + nlg][i] * sg;
        VST[nl * 192 + col * 3 + 2] = acc2[4 + nlg][i] * sg;
      }
    }
  }
  __syncthreads();  // B4: VST visible

  // ---- coalesced full-line V_out store (float4 x 64 lanes = 1KB/instr) ----
  {
    float4* Vo = (float4*)(V_out_g + n0 * 192);
    const float4* Vs = (const float4*)VST;
    #pragma unroll
    for (int i = 0; i < 6; ++i) {
      int idx = t + 256 * i;
      Vo[idx] = Vs[idx];
    }
  }
}

extern "C" void kernel_launch(void* const* d_in, const int* in_sizes, int n_in,
                              void* d_out, int out_size, void* d_ws, size_t ws_size,
                              hipStream_t stream) {
  const float* s_in  = (const float*)d_in[0];
  const float* V_in  = (const float*)d_in[1];
  const float* W_h   = (const float*)d_in[2];
  const float* W_V   = (const float*)d_in[3];
  const float* W_s_w = (const float*)d_in[4];
  const float* W_s_b = (const float*)d_in[5];
  const float* W_g_w = (const float*)d_in[6];
  const float* W_g_b = (const float*)d_in[7];
  float* out = (float*)d_out;
  float* s_out_g = out;
  float* V_out_g = out + (size_t)NNODES * 128;
  hipLaunchKernelGGL(prep_kernel, dim3(52), dim3(256), 0, stream,
                     W_h, W_V, W_s_w, W_g_w);
  hipLaunchKernelGGL(gvp_kernel, dim3(NNODES / BN), dim3(256), 0, stream,
                     s_in, V_in, W_s_b, W_g_b, s_out_g, V_out_g);
}

// Round 12
// 110.820 us; speedup vs baseline: 1.5504x; 1.5111x over previous
//
#include <hip/hip_runtime.h>
#include <hip/hip_bf16.h>
#include <math.h>

#define NNODES 131072
#define BN 32

typedef __attribute__((ext_vector_type(8))) short bf16x8;
typedef __attribute__((ext_vector_type(4))) float f32x4;

// bf16 weights (prep): W_h [128*64] @0 | W_s [128*256] @8192 | W_g [64*128] @40960
__device__ short g_w[49152];
// bf16 fused weight Wc[o][v] = sum_h W_V[o][h]*W_h[h][v], [64*64] row-major
__device__ short g_wc[4096];

__device__ __forceinline__ short f2b(float f) {
  union { float f; unsigned u; } x; x.f = f;
  unsigned r = x.u + 0x7fffu + ((x.u >> 16) & 1u);
  return (short)(r >> 16);
}
__device__ __forceinline__ short c2b(float f) {
  __hip_bfloat16 h = __float2bfloat16(f);
  return *reinterpret_cast<short*>(&h);
}

__global__ void prep_kernel(const float* __restrict__ W_h, const float* __restrict__ W_V,
                            const float* __restrict__ W_s_w, const float* __restrict__ W_g_w) {
  int b = blockIdx.x;
  if (b < 48) {
    int i4 = (b * 256 + threadIdx.x) * 4;
    const float* src;
    if (i4 < 8192)       src = W_h   + i4;
    else if (i4 < 40960) src = W_s_w + (i4 - 8192);
    else                 src = W_g_w + (i4 - 40960);
    float4 q = *(const float4*)src;
    short4 p;
    p.x = f2b(q.x); p.y = f2b(q.y); p.z = f2b(q.z); p.w = f2b(q.w);
    *(short4*)(g_w + i4) = p;
  } else {
    int gid = (b - 48) * 256 + threadIdx.x;   // 0..1023
    int o  = gid >> 4;
    int v0 = (gid & 15) * 4;
    float a0 = 0.f, a1 = 0.f, a2 = 0.f, a3 = 0.f;
    #pragma unroll 8
    for (int h = 0; h < 128; ++h) {
      float wv = W_V[o * 128 + h];
      float4 wh = *(const float4*)(W_h + h * 64 + v0);
      a0 += wv * wh.x; a1 += wv * wh.y; a2 += wv * wh.z; a3 += wv * wh.w;
    }
    short4 p;
    p.x = f2b(a0); p.y = f2b(a1); p.z = f2b(a2); p.w = f2b(a3);
    *(short4*)(g_wc + o * 64 + v0) = p;
  }
}

// LDS (28672 B -> 5 blocks/CU; with VGPR cap 102 -> 20 waves/CU, +25% vs R8):
//   Vt  @0     (12288): [96][64]  bf16 s128 swz  (alive until GEMM2 af re-reads)
//   SCN @12288 (16384): [32][256] bf16 s512 swz  (s cols 0-127 staged; norm cols 128-255)
//   SOUT overlays SCN bytes 0-8191 after B3a (SCN reads done)
//   VST [16][768B] f32 (12288) overlays Vt after B3a; V_out stored in 2 rounds
// GEMM2 DEFERRED after GEMM3 so acc1(48) dies before acc2(24)+acc3(16) peak
// -> register peak ~100 fits the 102 cap of __launch_bounds__(256,5).
// Barriers: B1(Vt/SCN-s), B2(norm), B3a(SCN+Vt reads done), B3b(SOUT),
//           B4a(VST r0), B4b(r0 read), B4c(VST r1).

__global__ __launch_bounds__(256, 5)
void gvp_kernel(const float* __restrict__ s_in, const float* __restrict__ V_in,
                const float* __restrict__ W_s_b, const float* __restrict__ W_g_b,
                float* __restrict__ s_out_g, float* __restrict__ V_out_g)
{
  __shared__ __align__(16) char smem[28672];
  char* const Vt   = smem;
  char* const VSTb = smem;
  char* const SCN  = smem + 12288;
  char* const SOUT = smem + 12288;

  const short* const g_wh = g_w;
  const short* const g_ws = g_w + 8192;
  const short* const g_wg = g_w + 40960;

  const int t    = threadIdx.x;
  const int lane = t & 63;
  const int w    = t >> 6;
  const int l15  = lane & 15;
  const int lk8  = (lane >> 4) << 3;  // 0,8,16,24 : k-offset of A/B frag
  const int r4   = (lane >> 4) << 2;  // 0,4,8,12  : row-offset of C frag
  const long n0  = (long)blockIdx.x * BN;

  // ---- stage V tile: thread (nl, vg) loads 24 contiguous floats of node nl ----
  {
    const int nl = t >> 3;        // 0..31
    const int vg = t & 7;         // 0..7
    const int v0 = vg << 3;       // 0,8,..,56
    const float* vp = V_in + (n0 + nl) * 192 + v0 * 3;   // 96B contiguous
    float fl[24];
    #pragma unroll
    for (int i = 0; i < 6; ++i) *(float4*)(fl + 4 * i) = *(const float4*)(vp + 4 * i);
    #pragma unroll
    for (int c = 0; c < 3; ++c) {
      int row = (c << 5) + nl;
      bf16x8 p;
      #pragma unroll
      for (int j = 0; j < 8; ++j) p[j] = c2b(fl[j * 3 + c]);
      unsigned a = (unsigned)(row * 128) + (((unsigned)(v0 * 2)) ^ (unsigned)((row & 7) << 4));
      *(bf16x8*)(Vt + a) = p;
    }
  }
  // ---- stage s tile -> SCN cols 0-127 ----
  {
    const int nl = t >> 3;
    const int kg = t & 7;
    const int k0 = kg << 4;       // 0,16,..,112
    const float* sp = s_in + (n0 + nl) * 128 + k0;       // 64B contiguous
    float4 q0 = *(const float4*)(sp);
    float4 q1 = *(const float4*)(sp + 4);
    float4 q2 = *(const float4*)(sp + 8);
    float4 q3 = *(const float4*)(sp + 12);
    bf16x8 pa, pb;
    pa[0] = c2b(q0.x); pa[1] = c2b(q0.y); pa[2] = c2b(q0.z); pa[3] = c2b(q0.w);
    pa[4] = c2b(q1.x); pa[5] = c2b(q1.y); pa[6] = c2b(q1.z); pa[7] = c2b(q1.w);
    pb[0] = c2b(q2.x); pb[1] = c2b(q2.y); pb[2] = c2b(q2.z); pb[3] = c2b(q2.w);
    pb[4] = c2b(q3.x); pb[5] = c2b(q3.y); pb[6] = c2b(q3.z); pb[7] = c2b(q3.w);
    unsigned sw = (unsigned)((nl & 7) << 4);
    *(bf16x8*)(SCN + nl * 512 + (((unsigned)(k0 * 2)) ^ sw))      = pa;
    *(bf16x8*)(SCN + nl * 512 + (((unsigned)(k0 * 2 + 16)) ^ sw)) = pb;
  }
  __syncthreads();  // B1: Vt + SCN-s visible

  // ---- GEMM1 only (Vh, 96x128 K=64); acc1 dies right after norm ----
  f32x4 acc1[6][2];
  #pragma unroll
  for (int rt = 0; rt < 6; ++rt) {
    f32x4 z = {0.f, 0.f, 0.f, 0.f};
    acc1[rt][0] = z; acc1[rt][1] = z;
  }
  {
    bf16x8 bf1[2][2];
    #pragma unroll
    for (int cc = 0; cc < 2; ++cc) {
      int h = ((2 * w + cc) << 4) + l15;
      #pragma unroll
      for (int ks = 0; ks < 2; ++ks)
        bf1[cc][ks] = *(const bf16x8*)(g_wh + h * 64 + (ks << 5) + lk8);
    }
    #pragma unroll
    for (int rt = 0; rt < 6; ++rt) {
      int row = (rt << 4) + l15;
      unsigned sw = (unsigned)((row & 7) << 4);
      bf16x8 af0 = *(const bf16x8*)(Vt + row * 128 + (((unsigned)(lk8 * 2)) ^ sw));
      bf16x8 af1 = *(const bf16x8*)(Vt + row * 128 + (((unsigned)((32 + lk8) * 2)) ^ sw));
      #pragma unroll
      for (int cc = 0; cc < 2; ++cc) {
        acc1[rt][cc] = __builtin_amdgcn_mfma_f32_16x16x32_bf16(af0, bf1[cc][0], acc1[rt][cc], 0, 0, 0);
        acc1[rt][cc] = __builtin_amdgcn_mfma_f32_16x16x32_bf16(af1, bf1[cc][1], acc1[rt][cc], 0, 0, 0);
      }
    }
  }

  // ---- Vh_norm -> SCN cols 128-255 (norm half untouched by anyone yet) ----
  #pragma unroll
  for (int cc = 0; cc < 2; ++cc) {
    int col = ((2 * w + cc) << 4) + l15;
    #pragma unroll
    for (int rt = 0; rt < 2; ++rt) {
      #pragma unroll
      for (int i = 0; i < 4; ++i) {
        int nl = (rt << 4) + r4 + i;
        float x0 = acc1[rt][cc][i];
        float x1 = acc1[rt + 2][cc][i];
        float x2 = acc1[rt + 4][cc][i];
        float nrm = sqrtf(x0 * x0 + x1 * x1 + x2 * x2);
        int k = 128 + col;
        unsigned a = (unsigned)(nl * 512) + (((unsigned)(k * 2)) ^ (unsigned)((nl & 7) << 4));
        *(short*)(SCN + a) = c2b(nrm);
      }
    }
  }
  __syncthreads();  // B2: norm visible (acc1 dead from here)

  // ---- GEMM3: s_out = relu(SCN·W_s^T + b); 32x128, K=256 ----
  f32x4 acc3[2][2];
  {
    f32x4 z = {0.f, 0.f, 0.f, 0.f};
    acc3[0][0] = z; acc3[0][1] = z; acc3[1][0] = z; acc3[1][1] = z;
  }
  #pragma unroll
  for (int ks = 0; ks < 8; ++ks) {
    bf16x8 b3[2];
    #pragma unroll
    for (int cc = 0; cc < 2; ++cc) {
      int o = (w << 5) + (cc << 4) + l15;
      b3[cc] = *(const bf16x8*)(g_ws + o * 256 + (ks << 5) + lk8);
    }
    #pragma unroll
    for (int rt = 0; rt < 2; ++rt) {
      int row = (rt << 4) + l15;
      unsigned sw = (unsigned)((row & 7) << 4);
      bf16x8 a = *(const bf16x8*)(SCN + row * 512 +
                   (((unsigned)(((ks << 5) + lk8) * 2)) ^ sw));
      acc3[rt][0] = __builtin_amdgcn_mfma_f32_16x16x32_bf16(a, b3[0], acc3[rt][0], 0, 0, 0);
      acc3[rt][1] = __builtin_amdgcn_mfma_f32_16x16x32_bf16(a, b3[1], acc3[rt][1], 0, 0, 0);
    }
  }

  // ---- GEMM2 (deferred): V_out_pre via fused Wc, af re-read from still-live Vt ----
  f32x4 acc2[6];
  #pragma unroll
  for (int rt = 0; rt < 6; ++rt) { f32x4 z = {0.f,0.f,0.f,0.f}; acc2[rt] = z; }
  {
    bf16x8 bc[2];
    int o = (w << 4) + l15;
    bc[0] = *(const bf16x8*)(g_wc + o * 64 + lk8);
    bc[1] = *(const bf16x8*)(g_wc + o * 64 + 32 + lk8);
    #pragma unroll
    for (int rt = 0; rt < 6; ++rt) {
      int row = (rt << 4) + l15;
      unsigned sw = (unsigned)((row & 7) << 4);
      bf16x8 af0 = *(const bf16x8*)(Vt + row * 128 + (((unsigned)(lk8 * 2)) ^ sw));
      bf16x8 af1 = *(const bf16x8*)(Vt + row * 128 + (((unsigned)((32 + lk8) * 2)) ^ sw));
      acc2[rt] = __builtin_amdgcn_mfma_f32_16x16x32_bf16(af0, bc[0], acc2[rt], 0, 0, 0);
      acc2[rt] = __builtin_amdgcn_mfma_f32_16x16x32_bf16(af1, bc[1], acc2[rt], 0, 0, 0);
    }
  }

  // ---- s_out global stores (no LDS; overlap with barrier drain) ----
  float so[2][2][4];
  {
    float bias0 = W_s_b[(w << 5) + l15];
    float bias1 = W_s_b[(w << 5) + 16 + l15];
    #pragma unroll
    for (int rt = 0; rt < 2; ++rt) {
      #pragma unroll
      for (int i = 0; i < 4; ++i) {
        int row = (rt << 4) + r4 + i;
        float v0 = fmaxf(acc3[rt][0][i] + bias0, 0.0f);
        float v1 = fmaxf(acc3[rt][1][i] + bias1, 0.0f);
        so[rt][0][i] = v0; so[rt][1][i] = v1;
        int col0 = (w << 5) + l15;
        s_out_g[(n0 + row) * 128 + col0]      = v0;
        s_out_g[(n0 + row) * 128 + col0 + 16] = v1;
      }
    }
  }
  __syncthreads();  // B3a: SCN reads (GEMM3) + Vt reads (GEMM2) done -> overlays allowed

  // ---- SOUT stage (overlays SCN bytes 0-8191) ----
  #pragma unroll
  for (int rt = 0; rt < 2; ++rt) {
    #pragma unroll
    for (int i = 0; i < 4; ++i) {
      int row = (rt << 4) + r4 + i;
      unsigned sw = (unsigned)((row & 7) << 4);
      int col0 = (w << 5) + l15;
      unsigned a0 = (unsigned)(row * 256) + (((unsigned)(col0 * 2)) ^ sw);
      unsigned a1 = (unsigned)(row * 256) + (((unsigned)((col0 + 16) * 2)) ^ sw);
      *(short*)(SOUT + a0) = c2b(so[rt][0][i]);
      *(short*)(SOUT + a1) = c2b(so[rt][1][i]);
    }
  }
  __syncthreads();  // B3b: SOUT ready

  // ---- GEMM4: gate = sigmoid(s_out·W_g^T + b); C-frag lane-aligned with acc2 ----
  f32x4 acc4[2];
  { f32x4 z = {0.f, 0.f, 0.f, 0.f}; acc4[0] = z; acc4[1] = z; }
  {
    int o = (w << 4) + l15;
    #pragma unroll
    for (int ks = 0; ks < 4; ++ks) {
      bf16x8 b4 = *(const bf16x8*)(g_wg + o * 128 + (ks << 5) + lk8);
      #pragma unroll
      for (int rt = 0; rt < 2; ++rt) {
        int row = (rt << 4) + l15;
        bf16x8 a = *(const bf16x8*)(SOUT + row * 256 +
                     (((unsigned)(((ks << 5) + lk8) * 2)) ^ ((unsigned)((row & 7) << 4))));
        acc4[rt] = __builtin_amdgcn_mfma_f32_16x16x32_bf16(a, b4, acc4[rt], 0, 0, 0);
      }
    }
  }
  float sg[2][4];
  {
    float biasg = W_g_b[(w << 4) + l15];
    #pragma unroll
    for (int nlg = 0; nlg < 2; ++nlg)
      #pragma unroll
      for (int i = 0; i < 4; ++i)
        sg[nlg][i] = 1.0f / (1.0f + __expf(-(acc4[nlg][i] + biasg)));
  }

  // ---- V_out in two 16-node rounds through VST [16][768B] (overlays Vt) ----
  #pragma unroll
  for (int r = 0; r < 2; ++r) {
    // gate apply: round r covers rt = {r, 2+r, 4+r} (nl = r*16 + r4+i), c = rt>>1
    {
      int col = (w << 4) + l15;
      #pragma unroll
      for (int c = 0; c < 3; ++c) {
        #pragma unroll
        for (int i = 0; i < 4; ++i) {
          int nl_rel = r4 + i;                 // 0..15
          unsigned sw = (unsigned)(nl_rel << 4);
          unsigned base = (unsigned)(nl_rel * 768);
          *(float*)(VSTb + base + (((unsigned)((col * 3 + c) * 4)) ^ sw)) =
              acc2[c * 2 + r][i] * sg[r][i];
        }
      }
    }
    __syncthreads();  // B4a/B4c: VST round r ready
    {
      float4* Vo = (float4*)(V_out_g + (n0 + (long)(r << 4)) * 192);
      #pragma unroll
      for (int j = 0; j < 3; ++j) {
        int f = j * 256 + t;                   // 0..767 flat float4 idx
        int nl_rel = (f * 1366) >> 16;         // f / 48 (exact for f < 768)
        int rem = f - nl_rel * 48;
        float4 q = *(const float4*)(VSTb + nl_rel * 768 +
                     (((unsigned)(rem * 16)) ^ ((unsigned)(nl_rel << 4))));
        Vo[f] = q;
      }
    }
    if (r == 0) __syncthreads();  // B4b: round-0 reads done before round-1 writes
  }
}

extern "C" void kernel_launch(void* const* d_in, const int* in_sizes, int n_in,
                              void* d_out, int out_size, void* d_ws, size_t ws_size,
                              hipStream_t stream) {
  const float* s_in  = (const float*)d_in[0];
  const float* V_in  = (const float*)d_in[1];
  const float* W_h   = (const float*)d_in[2];
  const float* W_V   = (const float*)d_in[3];
  const float* W_s_w = (const float*)d_in[4];
  const float* W_s_b = (const float*)d_in[5];
  const float* W_g_w = (const float*)d_in[6];
  const float* W_g_b = (const float*)d_in[7];
  float* out = (float*)d_out;
  float* s_out_g = out;
  float* V_out_g = out + (size_t)NNODES * 128;
  hipLaunchKernelGGL(prep_kernel, dim3(52), dim3(256), 0, stream,
                     W_h, W_V, W_s_w, W_g_w);
  hipLaunchKernelGGL(gvp_kernel, dim3(NNODES / BN), dim3(256), 0, stream,
                     s_in, V_in, W_s_b, W_g_b, s_out_g, V_out_g);
}

// Round 13
// 105.020 us; speedup vs baseline: 1.6360x; 1.0552x over previous
//
#include <hip/hip_runtime.h>
#include <hip/hip_bf16.h>
#include <math.h>

#define NNODES 131072
#define BN 32

typedef __attribute__((ext_vector_type(8))) short bf16x8;
typedef __attribute__((ext_vector_type(4))) float f32x4;

// bf16 weights (prep): W_h [128*64] @0 | W_s [128*256] @8192 | W_g [64*128] @40960
__device__ short g_w[49152];
// bf16 fused weight Wc[o][v] = sum_h W_V[o][h]*W_h[h][v], [64*64] row-major
__device__ short g_wc[4096];

__device__ __forceinline__ short f2b(float f) {
  union { float f; unsigned u; } x; x.f = f;
  unsigned r = x.u + 0x7fffu + ((x.u >> 16) & 1u);
  return (short)(r >> 16);
}
__device__ __forceinline__ short c2b(float f) {
  __hip_bfloat16 h = __float2bfloat16(f);
  return *reinterpret_cast<short*>(&h);
}

__global__ void prep_kernel(const float* __restrict__ W_h, const float* __restrict__ W_V,
                            const float* __restrict__ W_s_w, const float* __restrict__ W_g_w) {
  int b = blockIdx.x;
  if (b < 48) {
    int i4 = (b * 256 + threadIdx.x) * 4;
    const float* src;
    if (i4 < 8192)       src = W_h   + i4;
    else if (i4 < 40960) src = W_s_w + (i4 - 8192);
    else                 src = W_g_w + (i4 - 40960);
    float4 q = *(const float4*)src;
    short4 p;
    p.x = f2b(q.x); p.y = f2b(q.y); p.z = f2b(q.z); p.w = f2b(q.w);
    *(short4*)(g_w + i4) = p;
  } else {
    int gid = (b - 48) * 256 + threadIdx.x;   // 0..1023
    int o  = gid >> 4;
    int v0 = (gid & 15) * 4;
    float a0 = 0.f, a1 = 0.f, a2 = 0.f, a3 = 0.f;
    #pragma unroll 8
    for (int h = 0; h < 128; ++h) {
      float wv = W_V[o * 128 + h];
      float4 wh = *(const float4*)(W_h + h * 64 + v0);
      a0 += wv * wh.x; a1 += wv * wh.y; a2 += wv * wh.z; a3 += wv * wh.w;
    }
    short4 p;
    p.x = f2b(a0); p.y = f2b(a1); p.z = f2b(a2); p.w = f2b(a3);
    *(short4*)(g_wc + o * 64 + v0) = p;
  }
}

// R13 = R12 structure + ILP experiment:
//   __launch_bounds__(256,3) -> ~170 VGPR cap (R12's (256,5) squeezed VGPR to 48,
//   serializing the 16 W_s B-frag L2 loads inside GEMM3 -> exposed latency).
//   All GEMM3 B-frags (b3[8][2], 64 VGPR) + bf1 + bc hoisted right after B1 so
//   their L2 latency hides under GEMM1+norm.
// LDS (28672 B): Vt @0 (12288) | SCN @12288 (16384) | SOUT overlays SCN after B3a |
//   VST [16][768B] overlays Vt after B3a (V_out in 2 rounds).
// Barriers: B1, B2, B3a, B3b, B4a, B4b, B4c (as R12).

__global__ __launch_bounds__(256, 3)
void gvp_kernel(const float* __restrict__ s_in, const float* __restrict__ V_in,
                const float* __restrict__ W_s_b, const float* __restrict__ W_g_b,
                float* __restrict__ s_out_g, float* __restrict__ V_out_g)
{
  __shared__ __align__(16) char smem[28672];
  char* const Vt   = smem;
  char* const VSTb = smem;
  char* const SCN  = smem + 12288;
  char* const SOUT = smem + 12288;

  const short* const g_wh = g_w;
  const short* const g_ws = g_w + 8192;
  const short* const g_wg = g_w + 40960;

  const int t    = threadIdx.x;
  const int lane = t & 63;
  const int w    = t >> 6;
  const int l15  = lane & 15;
  const int lk8  = (lane >> 4) << 3;  // 0,8,16,24 : k-offset of A/B frag
  const int r4   = (lane >> 4) << 2;  // 0,4,8,12  : row-offset of C frag
  const long n0  = (long)blockIdx.x * BN;

  // ---- stage V tile: thread (nl, vg) loads 24 contiguous floats of node nl ----
  {
    const int nl = t >> 3;        // 0..31
    const int vg = t & 7;         // 0..7
    const int v0 = vg << 3;       // 0,8,..,56
    const float* vp = V_in + (n0 + nl) * 192 + v0 * 3;   // 96B contiguous
    float fl[24];
    #pragma unroll
    for (int i = 0; i < 6; ++i) *(float4*)(fl + 4 * i) = *(const float4*)(vp + 4 * i);
    #pragma unroll
    for (int c = 0; c < 3; ++c) {
      int row = (c << 5) + nl;
      bf16x8 p;
      #pragma unroll
      for (int j = 0; j < 8; ++j) p[j] = c2b(fl[j * 3 + c]);
      unsigned a = (unsigned)(row * 128) + (((unsigned)(v0 * 2)) ^ (unsigned)((row & 7) << 4));
      *(bf16x8*)(Vt + a) = p;
    }
  }
  // ---- stage s tile -> SCN cols 0-127 ----
  {
    const int nl = t >> 3;
    const int kg = t & 7;
    const int k0 = kg << 4;       // 0,16,..,112
    const float* sp = s_in + (n0 + nl) * 128 + k0;       // 64B contiguous
    float4 q0 = *(const float4*)(sp);
    float4 q1 = *(const float4*)(sp + 4);
    float4 q2 = *(const float4*)(sp + 8);
    float4 q3 = *(const float4*)(sp + 12);
    bf16x8 pa, pb;
    pa[0] = c2b(q0.x); pa[1] = c2b(q0.y); pa[2] = c2b(q0.z); pa[3] = c2b(q0.w);
    pa[4] = c2b(q1.x); pa[5] = c2b(q1.y); pa[6] = c2b(q1.z); pa[7] = c2b(q1.w);
    pb[0] = c2b(q2.x); pb[1] = c2b(q2.y); pb[2] = c2b(q2.z); pb[3] = c2b(q2.w);
    pb[4] = c2b(q3.x); pb[5] = c2b(q3.y); pb[6] = c2b(q3.z); pb[7] = c2b(q3.w);
    unsigned sw = (unsigned)((nl & 7) << 4);
    *(bf16x8*)(SCN + nl * 512 + (((unsigned)(k0 * 2)) ^ sw))      = pa;
    *(bf16x8*)(SCN + nl * 512 + (((unsigned)(k0 * 2 + 16)) ^ sw)) = pb;
  }
  __syncthreads();  // B1: Vt + SCN-s visible

  // ---- hoisted weight fragments: bf1 (GEMM1), b3 (GEMM3), bc (GEMM2) ----
  // b3's 16 L2 loads issue HERE; latency hides under GEMM1 + norm.
  bf16x8 bf1[2][2];
  #pragma unroll
  for (int cc = 0; cc < 2; ++cc) {
    int h = ((2 * w + cc) << 4) + l15;
    #pragma unroll
    for (int ks = 0; ks < 2; ++ks)
      bf1[cc][ks] = *(const bf16x8*)(g_wh + h * 64 + (ks << 5) + lk8);
  }
  bf16x8 b3[8][2];
  #pragma unroll
  for (int ks = 0; ks < 8; ++ks)
    #pragma unroll
    for (int cc = 0; cc < 2; ++cc) {
      int o = (w << 5) + (cc << 4) + l15;
      b3[ks][cc] = *(const bf16x8*)(g_ws + o * 256 + (ks << 5) + lk8);
    }
  bf16x8 bc[2];
  {
    int o = (w << 4) + l15;
    bc[0] = *(const bf16x8*)(g_wc + o * 64 + lk8);
    bc[1] = *(const bf16x8*)(g_wc + o * 64 + 32 + lk8);
  }

  // ---- GEMM1 only (Vh, 96x128 K=64); acc1 dies right after norm ----
  f32x4 acc1[6][2];
  #pragma unroll
  for (int rt = 0; rt < 6; ++rt) {
    f32x4 z = {0.f, 0.f, 0.f, 0.f};
    acc1[rt][0] = z; acc1[rt][1] = z;
  }
  #pragma unroll
  for (int rt = 0; rt < 6; ++rt) {
    int row = (rt << 4) + l15;
    unsigned sw = (unsigned)((row & 7) << 4);
    bf16x8 af0 = *(const bf16x8*)(Vt + row * 128 + (((unsigned)(lk8 * 2)) ^ sw));
    bf16x8 af1 = *(const bf16x8*)(Vt + row * 128 + (((unsigned)((32 + lk8) * 2)) ^ sw));
    #pragma unroll
    for (int cc = 0; cc < 2; ++cc) {
      acc1[rt][cc] = __builtin_amdgcn_mfma_f32_16x16x32_bf16(af0, bf1[cc][0], acc1[rt][cc], 0, 0, 0);
      acc1[rt][cc] = __builtin_amdgcn_mfma_f32_16x16x32_bf16(af1, bf1[cc][1], acc1[rt][cc], 0, 0, 0);
    }
  }

  // ---- Vh_norm -> SCN cols 128-255 ----
  #pragma unroll
  for (int cc = 0; cc < 2; ++cc) {
    int col = ((2 * w + cc) << 4) + l15;
    #pragma unroll
    for (int rt = 0; rt < 2; ++rt) {
      #pragma unroll
      for (int i = 0; i < 4; ++i) {
        int nl = (rt << 4) + r4 + i;
        float x0 = acc1[rt][cc][i];
        float x1 = acc1[rt + 2][cc][i];
        float x2 = acc1[rt + 4][cc][i];
        float nrm = sqrtf(x0 * x0 + x1 * x1 + x2 * x2);
        int k = 128 + col;
        unsigned a = (unsigned)(nl * 512) + (((unsigned)(k * 2)) ^ (unsigned)((nl & 7) << 4));
        *(short*)(SCN + a) = c2b(nrm);
      }
    }
  }
  __syncthreads();  // B2: norm visible (acc1 dead from here)

  // ---- GEMM3: s_out = relu(SCN·W_s^T + b); 32x128, K=256; B-frags pre-loaded ----
  f32x4 acc3[2][2];
  {
    f32x4 z = {0.f, 0.f, 0.f, 0.f};
    acc3[0][0] = z; acc3[0][1] = z; acc3[1][0] = z; acc3[1][1] = z;
  }
  #pragma unroll
  for (int ks = 0; ks < 8; ++ks) {
    #pragma unroll
    for (int rt = 0; rt < 2; ++rt) {
      int row = (rt << 4) + l15;
      unsigned sw = (unsigned)((row & 7) << 4);
      bf16x8 a = *(const bf16x8*)(SCN + row * 512 +
                   (((unsigned)(((ks << 5) + lk8) * 2)) ^ sw));
      acc3[rt][0] = __builtin_amdgcn_mfma_f32_16x16x32_bf16(a, b3[ks][0], acc3[rt][0], 0, 0, 0);
      acc3[rt][1] = __builtin_amdgcn_mfma_f32_16x16x32_bf16(a, b3[ks][1], acc3[rt][1], 0, 0, 0);
    }
  }

  // ---- GEMM2 (deferred): V_out_pre via fused Wc, af re-read from still-live Vt ----
  f32x4 acc2[6];
  #pragma unroll
  for (int rt = 0; rt < 6; ++rt) { f32x4 z = {0.f,0.f,0.f,0.f}; acc2[rt] = z; }
  #pragma unroll
  for (int rt = 0; rt < 6; ++rt) {
    int row = (rt << 4) + l15;
    unsigned sw = (unsigned)((row & 7) << 4);
    bf16x8 af0 = *(const bf16x8*)(Vt + row * 128 + (((unsigned)(lk8 * 2)) ^ sw));
    bf16x8 af1 = *(const bf16x8*)(Vt + row * 128 + (((unsigned)((32 + lk8) * 2)) ^ sw));
    acc2[rt] = __builtin_amdgcn_mfma_f32_16x16x32_bf16(af0, bc[0], acc2[rt], 0, 0, 0);
    acc2[rt] = __builtin_amdgcn_mfma_f32_16x16x32_bf16(af1, bc[1], acc2[rt], 0, 0, 0);
  }

  // ---- s_out global stores ----
  float so[2][2][4];
  {
    float bias0 = W_s_b[(w << 5) + l15];
    float bias1 = W_s_b[(w << 5) + 16 + l15];
    #pragma unroll
    for (int rt = 0; rt < 2; ++rt) {
      #pragma unroll
      for (int i = 0; i < 4; ++i) {
        int row = (rt << 4) + r4 + i;
        float v0 = fmaxf(acc3[rt][0][i] + bias0, 0.0f);
        float v1 = fmaxf(acc3[rt][1][i] + bias1, 0.0f);
        so[rt][0][i] = v0; so[rt][1][i] = v1;
        int col0 = (w << 5) + l15;
        s_out_g[(n0 + row) * 128 + col0]      = v0;
        s_out_g[(n0 + row) * 128 + col0 + 16] = v1;
      }
    }
  }
  __syncthreads();  // B3a: SCN reads (GEMM3) + Vt reads (GEMM2) done -> overlays allowed

  // ---- SOUT stage (overlays SCN bytes 0-8191) ----
  #pragma unroll
  for (int rt = 0; rt < 2; ++rt) {
    #pragma unroll
    for (int i = 0; i < 4; ++i) {
      int row = (rt << 4) + r4 + i;
      unsigned sw = (unsigned)((row & 7) << 4);
      int col0 = (w << 5) + l15;
      unsigned a0 = (unsigned)(row * 256) + (((unsigned)(col0 * 2)) ^ sw);
      unsigned a1 = (unsigned)(row * 256) + (((unsigned)((col0 + 16) * 2)) ^ sw);
      *(short*)(SOUT + a0) = c2b(so[rt][0][i]);
      *(short*)(SOUT + a1) = c2b(so[rt][1][i]);
    }
  }
  __syncthreads();  // B3b: SOUT ready

  // ---- GEMM4: gate = sigmoid(s_out·W_g^T + b); C-frag lane-aligned with acc2 ----
  f32x4 acc4[2];
  { f32x4 z = {0.f, 0.f, 0.f, 0.f}; acc4[0] = z; acc4[1] = z; }
  {
    int o = (w << 4) + l15;
    #pragma unroll
    for (int ks = 0; ks < 4; ++ks) {
      bf16x8 b4 = *(const bf16x8*)(g_wg + o * 128 + (ks << 5) + lk8);
      #pragma unroll
      for (int rt = 0; rt < 2; ++rt) {
        int row = (rt << 4) + l15;
        bf16x8 a = *(const bf16x8*)(SOUT + row * 256 +
                     (((unsigned)(((ks << 5) + lk8) * 2)) ^ ((unsigned)((row & 7) << 4))));
        acc4[rt] = __builtin_amdgcn_mfma_f32_16x16x32_bf16(a, b4, acc4[rt], 0, 0, 0);
      }
    }
  }
  float sg[2][4];
  {
    float biasg = W_g_b[(w << 4) + l15];
    #pragma unroll
    for (int nlg = 0; nlg < 2; ++nlg)
      #pragma unroll
      for (int i = 0; i < 4; ++i)
        sg[nlg][i] = 1.0f / (1.0f + __expf(-(acc4[nlg][i] + biasg)));
  }

  // ---- V_out in two 16-node rounds through VST [16][768B] (overlays Vt) ----
  #pragma unroll
  for (int r = 0; r < 2; ++r) {
    {
      int col = (w << 4) + l15;
      #pragma unroll
      for (int c = 0; c < 3; ++c) {
        #pragma unroll
        for (int i = 0; i < 4; ++i) {
          int nl_rel = r4 + i;                 // 0..15
          unsigned sw = (unsigned)(nl_rel << 4);
          unsigned base = (unsigned)(nl_rel * 768);
          *(float*)(VSTb + base + (((unsigned)((col * 3 + c) * 4)) ^ sw)) =
              acc2[c * 2 + r][i] * sg[r][i];
        }
      }
    }
    __syncthreads();  // B4a/B4c: VST round r ready
    {
      float4* Vo = (float4*)(V_out_g + (n0 + (long)(r << 4)) * 192);
      #pragma unroll
      for (int j = 0; j < 3; ++j) {
        int f = j * 256 + t;                   // 0..767 flat float4 idx
        int nl_rel = (f * 1366) >> 16;         // f / 48 (exact for f < 768)
        int rem = f - nl_rel * 48;
        float4 q = *(const float4*)(VSTb + nl_rel * 768 +
                     (((unsigned)(rem * 16)) ^ ((unsigned)(nl_rel << 4))));
        Vo[f] = q;
      }
    }
    if (r == 0) __syncthreads();  // B4b: round-0 reads done before round-1 writes
  }
}

extern "C" void kernel_launch(void* const* d_in, const int* in_sizes, int n_in,
                              void* d_out, int out_size, void* d_ws, size_t ws_size,
                              hipStream_t stream) {
  const float* s_in  = (const float*)d_in[0];
  const float* V_in  = (const float*)d_in[1];
  const float* W_h   = (const float*)d_in[2];
  const float* W_V   = (const float*)d_in[3];
  const float* W_s_w = (const float*)d_in[4];
  const float* W_s_b = (const float*)d_in[5];
  const float* W_g_w = (const float*)d_in[6];
  const float* W_g_b = (const float*)d_in[7];
  float* out = (float*)d_out;
  float* s_out_g = out;
  float* V_out_g = out + (size_t)NNODES * 128;
  hipLaunchKernelGGL(prep_kernel, dim3(52), dim3(256), 0, stream,
                     W_h, W_V, W_s_w, W_g_w);
  hipLaunchKernelGGL(gvp_kernel, dim3(NNODES / BN), dim3(256), 0, stream,
                     s_in, V_in, W_s_b, W_g_b, s_out_g, V_out_g);
}

// Round 14
// 102.950 us; speedup vs baseline: 1.6689x; 1.0201x over previous
//
#include <hip/hip_runtime.h>
#include <hip/hip_bf16.h>
#include <math.h>

#define NNODES 131072
#define BN 32

typedef __attribute__((ext_vector_type(8))) short bf16x8;
typedef __attribute__((ext_vector_type(4))) float f32x4;

// bf16 weights (prep): W_h [128*64] @0 | W_s [128*256] @8192 | W_g [64*128] @40960
__device__ short g_w[49152];
// bf16 fused weight Wc[o][v] = sum_h W_V[o][h]*W_h[h][v], [64*64] row-major
__device__ short g_wc[4096];

__device__ __forceinline__ short f2b(float f) {
  union { float f; unsigned u; } x; x.f = f;
  unsigned r = x.u + 0x7fffu + ((x.u >> 16) & 1u);
  return (short)(r >> 16);
}
__device__ __forceinline__ short c2b(float f) {
  __hip_bfloat16 h = __float2bfloat16(f);
  return *reinterpret_cast<short*>(&h);
}

__global__ void prep_kernel(const float* __restrict__ W_h, const float* __restrict__ W_V,
                            const float* __restrict__ W_s_w, const float* __restrict__ W_g_w) {
  int b = blockIdx.x;
  if (b < 48) {
    int i4 = (b * 256 + threadIdx.x) * 4;
    const float* src;
    if (i4 < 8192)       src = W_h   + i4;
    else if (i4 < 40960) src = W_s_w + (i4 - 8192);
    else                 src = W_g_w + (i4 - 40960);
    float4 q = *(const float4*)src;
    short4 p;
    p.x = f2b(q.x); p.y = f2b(q.y); p.z = f2b(q.z); p.w = f2b(q.w);
    *(short4*)(g_w + i4) = p;
  } else {
    int gid = (b - 48) * 256 + threadIdx.x;   // 0..1023
    int o  = gid >> 4;
    int v0 = (gid & 15) * 4;
    float a0 = 0.f, a1 = 0.f, a2 = 0.f, a3 = 0.f;
    #pragma unroll 8
    for (int h = 0; h < 128; ++h) {
      float wv = W_V[o * 128 + h];
      float4 wh = *(const float4*)(W_h + h * 64 + v0);
      a0 += wv * wh.x; a1 += wv * wh.y; a2 += wv * wh.z; a3 += wv * wh.w;
    }
    short4 p;
    p.x = f2b(a0); p.y = f2b(a1); p.z = f2b(a2); p.w = f2b(a3);
    *(short4*)(g_wc + o * 64 + v0) = p;
  }
}

// R14 = R13 + barrier/drain minimization:
//   * ALL global stores deferred past the last barrier (no vmcnt(0) barrier ever
//     drains a pending global store; s_out parks in 16 regs until kernel end).
//   * SOUT gets its own region; single full VST [32][192] f32 overlays Vt+SCN.
//   * Barriers 7 -> 4: B1 (Vt/SCN-s staged), B2 (norm), B3 (region-A reads done
//     + SOUT visible), B4 (VST visible).
// LDS 36864: Vt @0 (12288) | SCN @12288 (16384) | SOUT @28672 (8192)
//            VST @0 (24576 f32) overlays Vt + SCN rows 0-23 after B3.
// Weight frags hoisted: bf1/b3/bc after B1 (hide under GEMM1), b4 after B2.

__global__ __launch_bounds__(256, 3)
void gvp_kernel(const float* __restrict__ s_in, const float* __restrict__ V_in,
                const float* __restrict__ W_s_b, const float* __restrict__ W_g_b,
                float* __restrict__ s_out_g, float* __restrict__ V_out_g)
{
  __shared__ __align__(16) char smem[36864];
  char*  const Vt   = smem;
  float* const VST  = (float*)smem;
  char*  const SCN  = smem + 12288;
  char*  const SOUT = smem + 28672;

  const short* const g_wh = g_w;
  const short* const g_ws = g_w + 8192;
  const short* const g_wg = g_w + 40960;

  const int t    = threadIdx.x;
  const int lane = t & 63;
  const int w    = t >> 6;
  const int l15  = lane & 15;
  const int lk8  = (lane >> 4) << 3;  // 0,8,16,24 : k-offset of A/B frag
  const int r4   = (lane >> 4) << 2;  // 0,4,8,12  : row-offset of C frag
  const long n0  = (long)blockIdx.x * BN;

  // ---- stage V tile: thread (nl, vg) loads 24 contiguous floats of node nl ----
  {
    const int nl = t >> 3;        // 0..31
    const int vg = t & 7;         // 0..7
    const int v0 = vg << 3;       // 0,8,..,56
    const float* vp = V_in + (n0 + nl) * 192 + v0 * 3;   // 96B contiguous
    float fl[24];
    #pragma unroll
    for (int i = 0; i < 6; ++i) *(float4*)(fl + 4 * i) = *(const float4*)(vp + 4 * i);
    #pragma unroll
    for (int c = 0; c < 3; ++c) {
      int row = (c << 5) + nl;
      bf16x8 p;
      #pragma unroll
      for (int j = 0; j < 8; ++j) p[j] = c2b(fl[j * 3 + c]);
      unsigned a = (unsigned)(row * 128) + (((unsigned)(v0 * 2)) ^ (unsigned)((row & 7) << 4));
      *(bf16x8*)(Vt + a) = p;
    }
  }
  // ---- stage s tile -> SCN cols 0-127 ----
  {
    const int nl = t >> 3;
    const int kg = t & 7;
    const int k0 = kg << 4;       // 0,16,..,112
    const float* sp = s_in + (n0 + nl) * 128 + k0;       // 64B contiguous
    float4 q0 = *(const float4*)(sp);
    float4 q1 = *(const float4*)(sp + 4);
    float4 q2 = *(const float4*)(sp + 8);
    float4 q3 = *(const float4*)(sp + 12);
    bf16x8 pa, pb;
    pa[0] = c2b(q0.x); pa[1] = c2b(q0.y); pa[2] = c2b(q0.z); pa[3] = c2b(q0.w);
    pa[4] = c2b(q1.x); pa[5] = c2b(q1.y); pa[6] = c2b(q1.z); pa[7] = c2b(q1.w);
    pb[0] = c2b(q2.x); pb[1] = c2b(q2.y); pb[2] = c2b(q2.z); pb[3] = c2b(q2.w);
    pb[4] = c2b(q3.x); pb[5] = c2b(q3.y); pb[6] = c2b(q3.z); pb[7] = c2b(q3.w);
    unsigned sw = (unsigned)((nl & 7) << 4);
    *(bf16x8*)(SCN + nl * 512 + (((unsigned)(k0 * 2)) ^ sw))      = pa;
    *(bf16x8*)(SCN + nl * 512 + (((unsigned)(k0 * 2 + 16)) ^ sw)) = pb;
  }
  __syncthreads();  // B1: Vt + SCN-s visible (only input loads pending here)

  // ---- hoisted weight fragments: bf1 (GEMM1), b3 (GEMM3), bc (GEMM2) ----
  bf16x8 bf1[2][2];
  #pragma unroll
  for (int cc = 0; cc < 2; ++cc) {
    int h = ((2 * w + cc) << 4) + l15;
    #pragma unroll
    for (int ks = 0; ks < 2; ++ks)
      bf1[cc][ks] = *(const bf16x8*)(g_wh + h * 64 + (ks << 5) + lk8);
  }
  bf16x8 b3[8][2];
  #pragma unroll
  for (int ks = 0; ks < 8; ++ks)
    #pragma unroll
    for (int cc = 0; cc < 2; ++cc) {
      int o = (w << 5) + (cc << 4) + l15;
      b3[ks][cc] = *(const bf16x8*)(g_ws + o * 256 + (ks << 5) + lk8);
    }
  bf16x8 bc[2];
  {
    int o = (w << 4) + l15;
    bc[0] = *(const bf16x8*)(g_wc + o * 64 + lk8);
    bc[1] = *(const bf16x8*)(g_wc + o * 64 + 32 + lk8);
  }

  // ---- GEMM1 (Vh, 96x128 K=64); acc1 dies right after norm ----
  f32x4 acc1[6][2];
  #pragma unroll
  for (int rt = 0; rt < 6; ++rt) {
    f32x4 z = {0.f, 0.f, 0.f, 0.f};
    acc1[rt][0] = z; acc1[rt][1] = z;
  }
  #pragma unroll
  for (int rt = 0; rt < 6; ++rt) {
    int row = (rt << 4) + l15;
    unsigned sw = (unsigned)((row & 7) << 4);
    bf16x8 af0 = *(const bf16x8*)(Vt + row * 128 + (((unsigned)(lk8 * 2)) ^ sw));
    bf16x8 af1 = *(const bf16x8*)(Vt + row * 128 + (((unsigned)((32 + lk8) * 2)) ^ sw));
    #pragma unroll
    for (int cc = 0; cc < 2; ++cc) {
      acc1[rt][cc] = __builtin_amdgcn_mfma_f32_16x16x32_bf16(af0, bf1[cc][0], acc1[rt][cc], 0, 0, 0);
      acc1[rt][cc] = __builtin_amdgcn_mfma_f32_16x16x32_bf16(af1, bf1[cc][1], acc1[rt][cc], 0, 0, 0);
    }
  }

  // ---- Vh_norm -> SCN cols 128-255 ----
  #pragma unroll
  for (int cc = 0; cc < 2; ++cc) {
    int col = ((2 * w + cc) << 4) + l15;
    #pragma unroll
    for (int rt = 0; rt < 2; ++rt) {
      #pragma unroll
      for (int i = 0; i < 4; ++i) {
        int nl = (rt << 4) + r4 + i;
        float x0 = acc1[rt][cc][i];
        float x1 = acc1[rt + 2][cc][i];
        float x2 = acc1[rt + 4][cc][i];
        float nrm = sqrtf(x0 * x0 + x1 * x1 + x2 * x2);
        int k = 128 + col;
        unsigned a = (unsigned)(nl * 512) + (((unsigned)(k * 2)) ^ (unsigned)((nl & 7) << 4));
        *(short*)(SCN + a) = c2b(nrm);
      }
    }
  }
  __syncthreads();  // B2: norm visible (acc1 dead; no global ops pending)

  // ---- hoist GEMM4 weights under GEMM3 ----
  bf16x8 b4[4];
  {
    int o = (w << 4) + l15;
    #pragma unroll
    for (int ks = 0; ks < 4; ++ks)
      b4[ks] = *(const bf16x8*)(g_wg + o * 128 + (ks << 5) + lk8);
  }

  // ---- GEMM3: s_out = relu(SCN·W_s^T + b); 32x128, K=256; B-frags pre-loaded ----
  f32x4 acc3[2][2];
  {
    f32x4 z = {0.f, 0.f, 0.f, 0.f};
    acc3[0][0] = z; acc3[0][1] = z; acc3[1][0] = z; acc3[1][1] = z;
  }
  #pragma unroll
  for (int ks = 0; ks < 8; ++ks) {
    #pragma unroll
    for (int rt = 0; rt < 2; ++rt) {
      int row = (rt << 4) + l15;
      unsigned sw = (unsigned)((row & 7) << 4);
      bf16x8 a = *(const bf16x8*)(SCN + row * 512 +
                   (((unsigned)(((ks << 5) + lk8) * 2)) ^ sw));
      acc3[rt][0] = __builtin_amdgcn_mfma_f32_16x16x32_bf16(a, b3[ks][0], acc3[rt][0], 0, 0, 0);
      acc3[rt][1] = __builtin_amdgcn_mfma_f32_16x16x32_bf16(a, b3[ks][1], acc3[rt][1], 0, 0, 0);
    }
  }

  // ---- GEMM2 (deferred): V_out_pre via fused Wc, af re-read from still-live Vt ----
  f32x4 acc2[6];
  #pragma unroll
  for (int rt = 0; rt < 6; ++rt) { f32x4 z = {0.f,0.f,0.f,0.f}; acc2[rt] = z; }
  #pragma unroll
  for (int rt = 0; rt < 6; ++rt) {
    int row = (rt << 4) + l15;
    unsigned sw = (unsigned)((row & 7) << 4);
    bf16x8 af0 = *(const bf16x8*)(Vt + row * 128 + (((unsigned)(lk8 * 2)) ^ sw));
    bf16x8 af1 = *(const bf16x8*)(Vt + row * 128 + (((unsigned)((32 + lk8) * 2)) ^ sw));
    acc2[rt] = __builtin_amdgcn_mfma_f32_16x16x32_bf16(af0, bc[0], acc2[rt], 0, 0, 0);
    acc2[rt] = __builtin_amdgcn_mfma_f32_16x16x32_bf16(af1, bc[1], acc2[rt], 0, 0, 0);
  }

  // ---- s_out values -> regs (global store DEFERRED to kernel end) + SOUT stage ----
  float so[2][2][4];
  {
    float bias0 = W_s_b[(w << 5) + l15];
    float bias1 = W_s_b[(w << 5) + 16 + l15];
    #pragma unroll
    for (int rt = 0; rt < 2; ++rt) {
      #pragma unroll
      for (int i = 0; i < 4; ++i) {
        int row = (rt << 4) + r4 + i;
        unsigned sw = (unsigned)((row & 7) << 4);
        float v0 = fmaxf(acc3[rt][0][i] + bias0, 0.0f);
        float v1 = fmaxf(acc3[rt][1][i] + bias1, 0.0f);
        so[rt][0][i] = v0; so[rt][1][i] = v1;
        int col0 = (w << 5) + l15;
        unsigned a0 = (unsigned)(row * 256) + (((unsigned)(col0 * 2)) ^ sw);
        unsigned a1 = (unsigned)(row * 256) + (((unsigned)((col0 + 16) * 2)) ^ sw);
        *(short*)(SOUT + a0) = c2b(v0);
        *(short*)(SOUT + a1) = c2b(v1);
      }
    }
  }
  __syncthreads();  // B3: region-A reads (GEMM1/2/3) done for ALL waves; SOUT visible

  // ---- GEMM4: gate = sigmoid(s_out·W_g^T + b); C-frag lane-aligned with acc2 ----
  f32x4 acc4[2];
  { f32x4 z = {0.f, 0.f, 0.f, 0.f}; acc4[0] = z; acc4[1] = z; }
  #pragma unroll
  for (int ks = 0; ks < 4; ++ks) {
    #pragma unroll
    for (int rt = 0; rt < 2; ++rt) {
      int row = (rt << 4) + l15;
      bf16x8 a = *(const bf16x8*)(SOUT + row * 256 +
                   (((unsigned)(((ks << 5) + lk8) * 2)) ^ ((unsigned)((row & 7) << 4))));
      acc4[rt] = __builtin_amdgcn_mfma_f32_16x16x32_bf16(a, b4[ks], acc4[rt], 0, 0, 0);
    }
  }
  float sg[2][4];
  {
    float biasg = W_g_b[(w << 4) + l15];
    #pragma unroll
    for (int nlg = 0; nlg < 2; ++nlg)
      #pragma unroll
      for (int i = 0; i < 4; ++i)
        sg[nlg][i] = 1.0f / (1.0f + __expf(-(acc4[nlg][i] + biasg)));
  }

  // ---- gate apply -> full VST [32][192] f32 (overlays Vt + SCN rows 0-23) ----
  {
    int col = (w << 4) + l15;
    #pragma unroll
    for (int rt = 0; rt < 6; ++rt) {
      int c   = rt >> 1;
      int nlg = rt & 1;
      #pragma unroll
      for (int i = 0; i < 4; ++i) {
        int nl = (nlg << 4) + r4 + i;
        VST[nl * 192 + col * 3 + c] = acc2[rt][i] * sg[nlg][i];
      }
    }
  }
  __syncthreads();  // B4: VST visible (no global ops pending)

  // ---- all global stores AFTER the last barrier ----
  {
    float4* Vo = (float4*)(V_out_g + n0 * 192);
    const float4* Vs = (const float4*)VST;
    #pragma unroll
    for (int i = 0; i < 6; ++i) {
      int idx = t + 256 * i;
      Vo[idx] = Vs[idx];
    }
  }
  {
    int col0 = (w << 5) + l15;
    #pragma unroll
    for (int rt = 0; rt < 2; ++rt) {
      #pragma unroll
      for (int i = 0; i < 4; ++i) {
        int row = (rt << 4) + r4 + i;
        s_out_g[(n0 + row) * 128 + col0]      = so[rt][0][i];
        s_out_g[(n0 + row) * 128 + col0 + 16] = so[rt][1][i];
      }
    }
  }
}

extern "C" void kernel_launch(void* const* d_in, const int* in_sizes, int n_in,
                              void* d_out, int out_size, void* d_ws, size_t ws_size,
                              hipStream_t stream) {
  const float* s_in  = (const float*)d_in[0];
  const float* V_in  = (const float*)d_in[1];
  const float* W_h   = (const float*)d_in[2];
  const float* W_V   = (const float*)d_in[3];
  const float* W_s_w = (const float*)d_in[4];
  const float* W_s_b = (const float*)d_in[5];
  const float* W_g_w = (const float*)d_in[6];
  const float* W_g_b = (const float*)d_in[7];
  float* out = (float*)d_out;
  float* s_out_g = out;
  float* V_out_g = out + (size_t)NNODES * 128;
  hipLaunchKernelGGL(prep_kernel, dim3(52), dim3(256), 0, stream,
                     W_h, W_V, W_s_w, W_g_w);
  hipLaunchKernelGGL(gvp_kernel, dim3(NNODES / BN), dim3(256), 0, stream,
                     s_in, V_in, W_s_b, W_g_b, s_out_g, V_out_g);
}

// Round 15
// 95.556 us; speedup vs baseline: 1.7981x; 1.0774x over previous
//
#include <hip/hip_runtime.h>
#include <hip/hip_bf16.h>
#include <math.h>

#define NNODES 131072
#define BN 64

typedef __attribute__((ext_vector_type(8))) short bf16x8;
typedef __attribute__((ext_vector_type(4))) float f32x4;

// bf16 weights (prep): W_h [128*64] @0 | W_s [128*256] @8192 | W_g [64*128] @40960
__device__ short g_w[49152];
// bf16 fused weight Wc[o][v] = sum_h W_V[o][h]*W_h[h][v], [64*64] row-major
__device__ short g_wc[4096];

__device__ __forceinline__ short f2b(float f) {
  union { float f; unsigned u; } x; x.f = f;
  unsigned r = x.u + 0x7fffu + ((x.u >> 16) & 1u);
  return (short)(r >> 16);
}
__device__ __forceinline__ short c2b(float f) {
  __hip_bfloat16 h = __float2bfloat16(f);
  return *reinterpret_cast<short*>(&h);
}

__global__ void prep_kernel(const float* __restrict__ W_h, const float* __restrict__ W_V,
                            const float* __restrict__ W_s_w, const float* __restrict__ W_g_w) {
  int b = blockIdx.x;
  if (b < 48) {
    int i4 = (b * 256 + threadIdx.x) * 4;
    const float* src;
    if (i4 < 8192)       src = W_h   + i4;
    else if (i4 < 40960) src = W_s_w + (i4 - 8192);
    else                 src = W_g_w + (i4 - 40960);
    float4 q = *(const float4*)src;
    short4 p;
    p.x = f2b(q.x); p.y = f2b(q.y); p.z = f2b(q.z); p.w = f2b(q.w);
    *(short4*)(g_w + i4) = p;
  } else {
    int gid = (b - 48) * 256 + threadIdx.x;   // 0..1023
    int o  = gid >> 4;
    int v0 = (gid & 15) * 4;
    float a0 = 0.f, a1 = 0.f, a2 = 0.f, a3 = 0.f;
    #pragma unroll 8
    for (int h = 0; h < 128; ++h) {
      float wv = W_V[o * 128 + h];
      float4 wh = *(const float4*)(W_h + h * 64 + v0);
      a0 += wv * wh.x; a1 += wv * wh.y; a2 += wv * wh.z; a3 += wv * wh.w;
    }
    short4 p;
    p.x = f2b(a0); p.y = f2b(a1); p.z = f2b(a2); p.w = f2b(a3);
    *(short4*)(g_wc + o * 64 + v0) = p;
  }
}

// R15 = R14 structure scaled to BN=64, 8 waves (512 thr), 2048 blocks:
//   generations/CU ~7 -> 4; 16 waves/CU; barriers 6 per 64 nodes (was 8);
//   GEMM3 = 32 MFMA/wave; all global stores after the last barrier.
// LDS 57344 (2 blocks/CU):
//   Vt   @0     (24576): [192 rows = c*64+nl][128B] bf16 swz
//   SCN  @24576 (32768): [64][512B] bf16 swz (s cols 0-127, norm 128-255)
//   SOUT @24576 (16384): [64][256B] bf16 swz  (overlays SCN after B3)
//   VST  @0     (49152): [64][768B] f32 swz   (overlays all after B4a)
// Wave split: GEMM1/GEMM3 col group w (16 cols of 128);
//   GEMM2/GEMM4 col group w&3 (16 of 64) x node-half h2=w>>2 (nl 0-31 / 32-63).
// Barriers: B1 stage, B2 norm, B3 SCN/Vt reads done, B3b SOUT, B4a SOUT reads
//   done, B4b VST visible. No global store pending at any barrier.

__global__ __launch_bounds__(512, 2)
void gvp_kernel(const float* __restrict__ s_in, const float* __restrict__ V_in,
                const float* __restrict__ W_s_b, const float* __restrict__ W_g_b,
                float* __restrict__ s_out_g, float* __restrict__ V_out_g)
{
  __shared__ __align__(16) char smem[57344];
  char*  const Vt   = smem;
  float* const VST  = (float*)smem;
  char*  const SCN  = smem + 24576;
  char*  const SOUT = smem + 24576;

  const short* const g_wh = g_w;
  const short* const g_ws = g_w + 8192;
  const short* const g_wg = g_w + 40960;

  const int t    = threadIdx.x;
  const int lane = t & 63;
  const int w    = t >> 6;          // 0..7
  const int w4   = w & 3;
  const int h2   = w >> 2;          // node-half for GEMM2/4
  const int l15  = lane & 15;
  const int lk8  = (lane >> 4) << 3;  // 0,8,16,24
  const int r4   = (lane >> 4) << 2;  // 0,4,8,12
  const long n0  = (long)blockIdx.x * BN;

  // ---- stage V tile: thread (nl, vg) loads 24 contiguous floats of node nl ----
  {
    const int nl = t >> 3;        // 0..63
    const int vg = t & 7;
    const int v0 = vg << 3;
    const float* vp = V_in + (n0 + nl) * 192 + v0 * 3;   // 96B contiguous
    float fl[24];
    #pragma unroll
    for (int i = 0; i < 6; ++i) *(float4*)(fl + 4 * i) = *(const float4*)(vp + 4 * i);
    #pragma unroll
    for (int c = 0; c < 3; ++c) {
      int row = (c << 6) + nl;
      bf16x8 p;
      #pragma unroll
      for (int j = 0; j < 8; ++j) p[j] = c2b(fl[j * 3 + c]);
      unsigned a = (unsigned)(row * 128) + (((unsigned)(v0 * 2)) ^ (unsigned)((row & 7) << 4));
      *(bf16x8*)(Vt + a) = p;
    }
  }
  // ---- stage s tile -> SCN cols 0-127 ----
  {
    const int nl = t >> 3;
    const int kg = t & 7;
    const int k0 = kg << 4;
    const float* sp = s_in + (n0 + nl) * 128 + k0;       // 64B contiguous
    float4 q0 = *(const float4*)(sp);
    float4 q1 = *(const float4*)(sp + 4);
    float4 q2 = *(const float4*)(sp + 8);
    float4 q3 = *(const float4*)(sp + 12);
    bf16x8 pa, pb;
    pa[0] = c2b(q0.x); pa[1] = c2b(q0.y); pa[2] = c2b(q0.z); pa[3] = c2b(q0.w);
    pa[4] = c2b(q1.x); pa[5] = c2b(q1.y); pa[6] = c2b(q1.z); pa[7] = c2b(q1.w);
    pb[0] = c2b(q2.x); pb[1] = c2b(q2.y); pb[2] = c2b(q2.z); pb[3] = c2b(q2.w);
    pb[4] = c2b(q3.x); pb[5] = c2b(q3.y); pb[6] = c2b(q3.z); pb[7] = c2b(q3.w);
    unsigned sw = (unsigned)((nl & 7) << 4);
    *(bf16x8*)(SCN + nl * 512 + (((unsigned)(k0 * 2)) ^ sw))      = pa;
    *(bf16x8*)(SCN + nl * 512 + (((unsigned)(k0 * 2 + 16)) ^ sw)) = pb;
  }
  __syncthreads();  // B1

  // ---- hoisted weight fragments ----
  bf16x8 bf1[2];
  {
    int h = (w << 4) + l15;
    bf1[0] = *(const bf16x8*)(g_wh + h * 64 + lk8);
    bf1[1] = *(const bf16x8*)(g_wh + h * 64 + 32 + lk8);
  }
  bf16x8 b3[8];
  {
    int o = (w << 4) + l15;
    #pragma unroll
    for (int ks = 0; ks < 8; ++ks)
      b3[ks] = *(const bf16x8*)(g_ws + o * 256 + (ks << 5) + lk8);
  }
  bf16x8 bc[2];
  {
    int o = (w4 << 4) + l15;
    bc[0] = *(const bf16x8*)(g_wc + o * 64 + lk8);
    bc[1] = *(const bf16x8*)(g_wc + o * 64 + 32 + lk8);
  }

  // ---- GEMM1: Vh[c*64+nl][h], 192x128 K=64; wave w owns 16 h-cols ----
  f32x4 acc1[12];
  #pragma unroll
  for (int r = 0; r < 12; ++r) { f32x4 z = {0.f,0.f,0.f,0.f}; acc1[r] = z; }
  #pragma unroll
  for (int r = 0; r < 12; ++r) {
    int row = (r << 4) + l15;
    unsigned sw = (unsigned)((row & 7) << 4);
    bf16x8 af0 = *(const bf16x8*)(Vt + row * 128 + (((unsigned)(lk8 * 2)) ^ sw));
    bf16x8 af1 = *(const bf16x8*)(Vt + row * 128 + (((unsigned)((32 + lk8) * 2)) ^ sw));
    acc1[r] = __builtin_amdgcn_mfma_f32_16x16x32_bf16(af0, bf1[0], acc1[r], 0, 0, 0);
    acc1[r] = __builtin_amdgcn_mfma_f32_16x16x32_bf16(af1, bf1[1], acc1[r], 0, 0, 0);
  }

  // ---- Vh_norm -> SCN cols 128-255 (combine c-groups r = c*4+q) ----
  {
    int col = 128 + (w << 4) + l15;
    #pragma unroll
    for (int q = 0; q < 4; ++q) {
      #pragma unroll
      for (int i = 0; i < 4; ++i) {
        int nl = (q << 4) + r4 + i;
        float x0 = acc1[q][i];
        float x1 = acc1[4 + q][i];
        float x2 = acc1[8 + q][i];
        float nrm = sqrtf(x0 * x0 + x1 * x1 + x2 * x2);
        unsigned a = (unsigned)(nl * 512) + (((unsigned)(col * 2)) ^ (unsigned)((nl & 7) << 4));
        *(short*)(SCN + a) = c2b(nrm);
      }
    }
  }
  __syncthreads();  // B2 (acc1 dead)

  // ---- hoist GEMM4 weights under GEMM3 ----
  bf16x8 b4[4];
  {
    int o = (w4 << 4) + l15;
    #pragma unroll
    for (int ks = 0; ks < 4; ++ks)
      b4[ks] = *(const bf16x8*)(g_wg + o * 128 + (ks << 5) + lk8);
  }

  // ---- GEMM3: s_out 64x128 K=256; wave w owns 16 cols; 32 MFMA ----
  f32x4 acc3[4];
  #pragma unroll
  for (int rt = 0; rt < 4; ++rt) { f32x4 z = {0.f,0.f,0.f,0.f}; acc3[rt] = z; }
  #pragma unroll
  for (int ks = 0; ks < 8; ++ks) {
    #pragma unroll
    for (int rt = 0; rt < 4; ++rt) {
      int row = (rt << 4) + l15;
      unsigned sw = (unsigned)((row & 7) << 4);
      bf16x8 a = *(const bf16x8*)(SCN + row * 512 +
                   (((unsigned)(((ks << 5) + lk8) * 2)) ^ sw));
      acc3[rt] = __builtin_amdgcn_mfma_f32_16x16x32_bf16(a, b3[ks], acc3[rt], 0, 0, 0);
    }
  }

  // ---- GEMM2 (fused Wc): cols w4, node-half h2; rows r = c*4 + (2*h2+j) ----
  f32x4 acc2[3][2];
  #pragma unroll
  for (int c = 0; c < 3; ++c)
    #pragma unroll
    for (int j = 0; j < 2; ++j) { f32x4 z = {0.f,0.f,0.f,0.f}; acc2[c][j] = z; }
  #pragma unroll
  for (int c = 0; c < 3; ++c) {
    #pragma unroll
    for (int j = 0; j < 2; ++j) {
      int r = c * 4 + 2 * h2 + j;
      int row = (r << 4) + l15;
      unsigned sw = (unsigned)((row & 7) << 4);
      bf16x8 af0 = *(const bf16x8*)(Vt + row * 128 + (((unsigned)(lk8 * 2)) ^ sw));
      bf16x8 af1 = *(const bf16x8*)(Vt + row * 128 + (((unsigned)((32 + lk8) * 2)) ^ sw));
      acc2[c][j] = __builtin_amdgcn_mfma_f32_16x16x32_bf16(af0, bc[0], acc2[c][j], 0, 0, 0);
      acc2[c][j] = __builtin_amdgcn_mfma_f32_16x16x32_bf16(af1, bc[1], acc2[c][j], 0, 0, 0);
    }
  }

  // ---- s_out values -> regs (stores deferred to kernel end) ----
  float so[4][4];
  {
    float bias = W_s_b[(w << 4) + l15];
    #pragma unroll
    for (int rt = 0; rt < 4; ++rt)
      #pragma unroll
      for (int i = 0; i < 4; ++i)
        so[rt][i] = fmaxf(acc3[rt][i] + bias, 0.0f);
  }
  __syncthreads();  // B3: SCN reads (GEMM3) + Vt reads (GEMM2) done

  // ---- SOUT stage (overlays SCN) ----
  {
    int col = (w << 4) + l15;
    #pragma unroll
    for (int rt = 0; rt < 4; ++rt) {
      #pragma unroll
      for (int i = 0; i < 4; ++i) {
        int row = (rt << 4) + r4 + i;
        unsigned a = (unsigned)(row * 256) + (((unsigned)(col * 2)) ^ (unsigned)((row & 7) << 4));
        *(short*)(SOUT + a) = c2b(so[rt][i]);
      }
    }
  }
  __syncthreads();  // B3b: SOUT visible

  // ---- GEMM4: gate logits; cols w4, rows rt = 2*h2+j ----
  f32x4 acc4[2];
  { f32x4 z = {0.f,0.f,0.f,0.f}; acc4[0] = z; acc4[1] = z; }
  #pragma unroll
  for (int ks = 0; ks < 4; ++ks) {
    #pragma unroll
    for (int j = 0; j < 2; ++j) {
      int row = ((2 * h2 + j) << 4) + l15;
      bf16x8 a = *(const bf16x8*)(SOUT + row * 256 +
                   (((unsigned)(((ks << 5) + lk8) * 2)) ^ ((unsigned)((row & 7) << 4))));
      acc4[j] = __builtin_amdgcn_mfma_f32_16x16x32_bf16(a, b4[ks], acc4[j], 0, 0, 0);
    }
  }
  float sg[2][4];
  {
    float biasg = W_g_b[(w4 << 4) + l15];
    #pragma unroll
    for (int j = 0; j < 2; ++j)
      #pragma unroll
      for (int i = 0; i < 4; ++i)
        sg[j][i] = 1.0f / (1.0f + __expf(-(acc4[j][i] + biasg)));
  }
  __syncthreads();  // B4a: SOUT reads done -> VST overlay allowed

  // ---- gate apply -> VST [64][768B] f32 swz (single write phase) ----
  {
    int col = (w4 << 4) + l15;
    #pragma unroll
    for (int c = 0; c < 3; ++c) {
      #pragma unroll
      for (int j = 0; j < 2; ++j) {
        #pragma unroll
        for (int i = 0; i < 4; ++i) {
          int nl = ((2 * h2 + j) << 4) + r4 + i;
          unsigned a = (unsigned)(nl * 768) +
                       (((unsigned)((col * 3 + c) * 4)) ^ (unsigned)((nl & 7) << 4));
          *(float*)((char*)VST + a) = acc2[c][j][i] * sg[j][i];
        }
      }
    }
  }
  __syncthreads();  // B4b: VST visible

  // ---- all global stores AFTER the last barrier ----
  {
    float4* Vo = (float4*)(V_out_g + n0 * 192);
    #pragma unroll
    for (int m = 0; m < 6; ++m) {
      int f = m * 512 + t;                 // 0..3071 flat float4 idx
      int nl = f / 48;
      int rem = f - nl * 48;
      float4 q = *(const float4*)((char*)VST + nl * 768 +
                   (((unsigned)(rem * 16)) ^ ((unsigned)((nl & 7) << 4))));
      Vo[f] = q;
    }
  }
  {
    int col = (w << 4) + l15;
    #pragma unroll
    for (int rt = 0; rt < 4; ++rt) {
      #pragma unroll
      for (int i = 0; i < 4; ++i) {
        int nl = (rt << 4) + r4 + i;
        s_out_g[(n0 + nl) * 128 + col] = so[rt][i];
      }
    }
  }
}

extern "C" void kernel_launch(void* const* d_in, const int* in_sizes, int n_in,
                              void* d_out, int out_size, void* d_ws, size_t ws_size,
                              hipStream_t stream) {
  const float* s_in  = (const float*)d_in[0];
  const float* V_in  = (const float*)d_in[1];
  const float* W_h   = (const float*)d_in[2];
  const float* W_V   = (const float*)d_in[3];
  const float* W_s_w = (const float*)d_in[4];
  const float* W_s_b = (const float*)d_in[5];
  const float* W_g_w = (const float*)d_in[6];
  const float* W_g_b = (const float*)d_in[7];
  float* out = (float*)d_out;
  float* s_out_g = out;
  float* V_out_g = out + (size_t)NNODES * 128;
  hipLaunchKernelGGL(prep_kernel, dim3(52), dim3(256), 0, stream,
                     W_h, W_V, W_s_w, W_g_w);
  hipLaunchKernelGGL(gvp_kernel, dim3(NNODES / BN), dim3(512), 0, stream,
                     s_in, V_in, W_s_b, W_g_b, s_out_g, V_out_g);
}